// Round 16
// baseline (303.425 us; speedup 1.0000x reference)
//
#include <hip/hip_runtime.h>
#include <hip/hip_bf16.h>

#define N_NODES 50000
#define N_EDGES 800000
#define N_TOT   (N_EDGES + N_NODES)
#define N_GRAPHS 256
#define F_IN 310
#define KP1 320          // F_IN padded to multiple of 32
#define CH 256
#define HID 128
#define CST 264          // LDS C-tile row stride (ushorts)

typedef __attribute__((ext_vector_type(8))) short short8;
typedef __attribute__((ext_vector_type(4))) float f32x4;
typedef unsigned short ushort_t;

__device__ __forceinline__ float selu_f(float x) {
    const float scale = 1.0507009873554805f;
    const float alpha = 1.6732632423543772f;
    return x > 0.f ? scale * x : scale * alpha * (expm1f(x));
}

__device__ __forceinline__ ushort_t f32_to_bf16_rne(float f) {
    unsigned u = __float_as_uint(f);
    unsigned rounding = 0x7FFFu + ((u >> 16) & 1u);
    return (ushort_t)((u + rounding) >> 16);
}
__device__ __forceinline__ float bf16_to_f32(ushort_t v) {
    return __uint_as_float(((unsigned)v) << 16);
}

// ---- W conversions + deg_count fused into one launch -----------------------
#define WT_BLKS ((CH * KP1 + CH * CH + 255) / 256)
__global__ __launch_bounds__(256) void convert_wt_deg(
        const float* __restrict__ W1, ushort_t* __restrict__ W1t,
        const float* __restrict__ W2, ushort_t* __restrict__ W2t,
        const int* __restrict__ ei, int* __restrict__ deg) {
    int b = blockIdx.x;
    if (b < WT_BLKS) {
        int i = b * 256 + threadIdx.x;
        const int n1 = CH * KP1;
        if (i < n1) {
            int n = i / KP1, k = i % KP1;
            W1t[i] = (k < F_IN) ? f32_to_bf16_rne(W1[(long)k * CH + n]) : 0;
        } else {
            int j = i - n1;
            if (j >= CH * CH) return;
            int n = j / CH, k = j % CH;
            W2t[j] = f32_to_bf16_rne(W2[(long)k * CH + n]);
        }
    } else {
        int eid = (b - WT_BLKS) * 256 + threadIdx.x;
        if (eid >= N_TOT) return;
        int d = (eid < N_EDGES) ? ei[N_EDGES + eid] : eid - N_EDGES;
        atomicAdd(&deg[d], 1);
    }
}

// ---- CSR reserve: per-node region [counter:int][slots:ushort*deg] ----------
// Region base (in 4B words) via atomic cursor. Counter init 1 (slot 0 =
// self-loop, filled without atomic). Colocating counter+slots makes the
// fill's RMW and store hit the SAME 64B sector (halves fill traffic).
__global__ __launch_bounds__(256) void reserve_k(
        const int* __restrict__ deg, int* __restrict__ basebuf,
        int* __restrict__ csrbuf, int* __restrict__ cursor, int n) {
    int i = blockIdx.x * blockDim.x + threadIdx.x;
    if (i >= n) return;
    int dgi = deg[i];
    int words = 1 + ((dgi + 1) >> 1);
    int b = atomicAdd(cursor, words);
    basebuf[i] = b;
    csrbuf[b] = 1;               // counter: slot 0 reserved for self-loop
}

// ------- MFMA GEMM 64x256 tile (4 waves of 64x64), counted-vmcnt 2-phase ----
// K-loop: stage(next) -> asm vmcnt(N_inflight) + raw s_barrier (prior tile
// ready, next tile's loads SPAN the barrier) -> ds_read+MFMA -> lgkmcnt(0) +
// raw s_barrier. Replaces __syncthreads' vmcnt(0) drain (all pipes were idle:
// MfmaUtil 4% convoy). FILL=1: extra blocks do the embedded-CSR fill.
template<int AF32, int FILL>
__global__ __launch_bounds__(256, 4) void gemm_k(
        const void* __restrict__ Asrc, const ushort_t* __restrict__ Bt,
        ushort_t* __restrict__ Cb, const float* __restrict__ att_l,
        const float* __restrict__ att_r, float* __restrict__ a_srcv,
        float* __restrict__ a_dstv, int M, int Kp, int gemmBlocks,
        const int* __restrict__ ei, const int* __restrict__ basebuf,
        int* __restrict__ csrbuf) {
    __shared__ __align__(16) ushort_t smem[20480];            // 40 KB
    ushort_t (*As)[2048] = reinterpret_cast<ushort_t(*)[2048]>(smem);
    ushort_t (*Bs)[8192] = reinterpret_cast<ushort_t(*)[8192]>(smem + 4096);
    int tid = threadIdx.x;

    if constexpr (FILL) {
        if ((int)blockIdx.x >= gemmBlocks) {            // ---- csr fill path
            int eid = ((int)blockIdx.x - gemmBlocks) * 256 + tid;
            if (eid < N_TOT) {
                if (eid < N_EDGES) {
                    int s = ei[eid], d = ei[N_EDGES + eid];
                    int b = basebuf[d];
                    int p = atomicAdd(&csrbuf[b], 1);   // same sector as slots
                    ((ushort_t*)csrbuf)[2 * (b + 1) + p] = (ushort_t)s;
                } else {
                    int d = eid - N_EDGES;              // self-loop: slot 0
                    ((ushort_t*)csrbuf)[2 * (basebuf[d] + 1)] = (ushort_t)d;
                }
            }
            return;
        }
    }

    int row0 = blockIdx.x * 64;
    int w = tid >> 6, l = tid & 63;       // wave w = output col-block
    int lr = l & 15, lc = l >> 4;
    f32x4 acc[4][4] = {};

    int srow = l >> 2;                    // 0..15
    int sc = l & 3;
    int sx = sc ^ (srow & 3) ^ ((srow >> 2) & 3);       // pre-swizzled chunk
    int garow = row0 + w * 16 + srow; if (garow >= M) garow = M - 1;
    const ushort_t* gB[4];
#pragma unroll
    for (int g = 0; g < 4; ++g)
        gB[g] = Bt + (size_t)(w * 64 + g * 16 + srow) * Kp + sx * 8;
    int nt = Kp >> 5;

    const ushort_t* gA = nullptr;
    const float* xrow = nullptr;
    if (AF32) xrow = (const float*)Asrc + (size_t)garow * F_IN;
    else      gA = (const ushort_t*)Asrc + (size_t)garow * Kp + sx * 8;

    auto stageB = [&](int sel, int k0) {
#pragma unroll
        for (int g = 0; g < 4; ++g)
            __builtin_amdgcn_global_load_lds(
                (const __attribute__((address_space(1))) void*)(gB[g] + k0),
                (__attribute__((address_space(3))) void*)(&Bs[sel][(w * 64 + g * 16) * 32]), 16, 0, 0);
    };
    auto stageA_glds = [&](int sel, int k0) {
        __builtin_amdgcn_global_load_lds(
            (const __attribute__((address_space(1))) void*)(gA + k0),
            (__attribute__((address_space(3))) void*)(&As[sel][w * 16 * 32]), 16, 0, 0);
    };
    float va[8];
    auto loadA_f32 = [&](int k0) {
        int kc = k0 + sc * 8;
        if (kc + 8 <= F_IN) {             // x rows are 8B-aligned: float2 ok
#pragma unroll
            for (int j = 0; j < 4; ++j) {
                float2 p = *(const float2*)(xrow + kc + j * 2);
                va[j * 2] = p.x; va[j * 2 + 1] = p.y;
            }
        } else {                          // K tail (cols >= 310 -> 0)
#pragma unroll
            for (int j = 0; j < 8; ++j)
                va[j] = (kc + j < F_IN) ? xrow[kc + j] : 0.f;
        }
    };
    auto writeA = [&](int sel) {
        short8 s;
#pragma unroll
        for (int j = 0; j < 8; ++j) s[j] = (short)f32_to_bf16_rne(va[j]);
        *(short8*)(&As[sel][(w * 16 + srow) * 32 + sx * 8]) = s;
    };

    // prologue: tile 0 fully staged + drained
    if (AF32) loadA_f32(0); else stageA_glds(0, 0);
    stageB(0, 0);
    if (AF32) writeA(0);
    asm volatile("s_waitcnt vmcnt(0) lgkmcnt(0)" ::: "memory");
    __builtin_amdgcn_s_barrier();

    int cur = 0;
    for (int t = 0; t < nt; ++t) {
        int k1 = (t + 1) << 5;
        bool more = (t + 1 < nt);
        if (more) {
            if (AF32) loadA_f32(k1); else stageA_glds(cur ^ 1, k1);
            stageB(cur ^ 1, k1);
        }
        // wait for PRIOR tile's loads only; next tile's stay in flight
        if (more) {
            if constexpr (AF32) asm volatile("s_waitcnt vmcnt(8)" ::: "memory");
            else                asm volatile("s_waitcnt vmcnt(5)" ::: "memory");
        } else {
            asm volatile("s_waitcnt vmcnt(0)" ::: "memory");
        }
        __builtin_amdgcn_s_barrier();

        short8 af[4], bfv[4];
#pragma unroll
        for (int mi = 0; mi < 4; ++mi) {
            int r = mi * 16 + lr;
            af[mi] = *(const short8*)(&As[cur][r * 32 + ((lc ^ (r & 3) ^ ((r >> 2) & 3)) * 8)]);
        }
#pragma unroll
        for (int ni = 0; ni < 4; ++ni) {
            int r = w * 64 + ni * 16 + lr;
            bfv[ni] = *(const short8*)(&Bs[cur][r * 32 + ((lc ^ (r & 3) ^ ((r >> 2) & 3)) * 8)]);
        }
        // swapped operands: lane holds row m = mi*16+lr, 4 consecutive cols
#pragma unroll
        for (int mi = 0; mi < 4; ++mi)
#pragma unroll
            for (int ni = 0; ni < 4; ++ni)
                acc[mi][ni] = __builtin_amdgcn_mfma_f32_16x16x32_bf16(
                    bfv[ni], af[mi], acc[mi][ni], 0, 0, 0);
        if (AF32 && more) writeA(cur ^ 1);
        asm volatile("s_waitcnt lgkmcnt(0)" ::: "memory");
        __builtin_amdgcn_s_barrier();
        cur ^= 1;
    }

    // ---- epilogue: LDS C-tile stage + att partials -------------------------
    ushort_t* Ct  = smem;                       // [64][CST] = 33792 B
    float*    s_pw = (float*)(smem + 17024);    // byte 34048: [2][4][64]
    float pl[4] = {}, pr[4] = {};
#pragma unroll
    for (int ni = 0; ni < 4; ++ni) {
        float4 alv = *(const float4*)(att_l + w * 64 + ni * 16 + lc * 4);
        float4 arv = *(const float4*)(att_r + w * 64 + ni * 16 + lc * 4);
#pragma unroll
        for (int mi = 0; mi < 4; ++mi) {
            f32x4 v = acc[mi][ni];
            pl[mi] += v[0] * alv.x + v[1] * alv.y + v[2] * alv.z + v[3] * alv.w;
            pr[mi] += v[0] * arv.x + v[1] * arv.y + v[2] * arv.z + v[3] * arv.w;
            ushort4 cv;
            cv.x = f32_to_bf16_rne(v[0]); cv.y = f32_to_bf16_rne(v[1]);
            cv.z = f32_to_bf16_rne(v[2]); cv.w = f32_to_bf16_rne(v[3]);
            *(ushort4*)(Ct + (mi * 16 + lr) * CST + w * 64 + ni * 16 + lc * 4) = cv;
        }
    }
#pragma unroll
    for (int mi = 0; mi < 4; ++mi) {
        pl[mi] += __shfl_xor(pl[mi], 16); pl[mi] += __shfl_xor(pl[mi], 32);
        pr[mi] += __shfl_xor(pr[mi], 16); pr[mi] += __shfl_xor(pr[mi], 32);
    }
    if (l < 16) {
#pragma unroll
        for (int mi = 0; mi < 4; ++mi) {
            s_pw[w * 64 + mi * 16 + lr]       = pl[mi];
            s_pw[256 + w * 64 + mi * 16 + lr] = pr[mi];
        }
    }
    __syncthreads();
    // coalesced C store: 64 rows x 256 cols as 16B chunks
#pragma unroll
    for (int it = 0; it < 8; ++it) {
        int id = it * 256 + tid;
        int r = id >> 5, c8 = (id & 31) * 8;
        int grow = row0 + r;
        if (grow < M) {
            short8 v = *(const short8*)(Ct + r * CST + c8);
            *(short8*)(Cb + (size_t)grow * CH + c8) = v;
        }
    }
    if (tid < 64) {
        int grow = row0 + tid;
        if (grow < M) {
            a_srcv[grow] = s_pw[tid] + s_pw[64 + tid] + s_pw[128 + tid] + s_pw[192 + tid];
            a_dstv[grow] = s_pw[256 + tid] + s_pw[320 + tid] + s_pw[384 + tid] + s_pw[448 + tid];
        }
    }
}

// ---- fused per-dst GAT aggregate: SINGLE edge pass (embedded CSR) ----------
__global__ __launch_bounds__(256) void gat_aggregate(
        const int* __restrict__ basebuf, const int* __restrict__ deg,
        const int* __restrict__ csrbuf,
        const float* __restrict__ a_src, const float* __restrict__ a_dst,
        const ushort_t* __restrict__ h, const float* __restrict__ bias,
        ushort_t* __restrict__ out_bf, int n) {
    int wid = threadIdx.x >> 6;
    int lane = threadIdx.x & 63;
    int node = blockIdx.x * 4 + wid;
    if (node >= n) return;
    const ushort_t* csr = (const ushort_t*)csrbuf;
    int s0 = 2 * (basebuf[node] + 1);
    int dg = deg[node];
    float ad = a_dst[node];

    float sum_l = 0.f;
    float4 acc = {0.f, 0.f, 0.f, 0.f};
    for (int c = 0; c < dg; c += 64) {
        int nc = min(64, dg - c);
        int s_l = 0; float ex_l = 0.f;
        if (lane < nc) {
            s_l = csr[s0 + c + lane];
            float e = a_src[s_l] + ad;
            e = fmaxf(e, 0.2f * e);
            ex_l = __expf(e);
            sum_l += ex_l;
        }
        int j = 0;
        for (; j + 8 <= nc; j += 8) {
            int si[8]; float xi[8]; ushort4 hv[8];
#pragma unroll
            for (int k = 0; k < 8; ++k) {
                si[k] = __shfl(s_l, j + k);
                xi[k] = __shfl(ex_l, j + k);
            }
#pragma unroll
            for (int k = 0; k < 8; ++k)
                hv[k] = *(const ushort4*)(h + (long)si[k] * CH + lane * 4);
#pragma unroll
            for (int k = 0; k < 8; ++k) {
                acc.x += xi[k] * bf16_to_f32(hv[k].x);
                acc.y += xi[k] * bf16_to_f32(hv[k].y);
                acc.z += xi[k] * bf16_to_f32(hv[k].z);
                acc.w += xi[k] * bf16_to_f32(hv[k].w);
            }
        }
        for (; j < nc; ++j) {
            int sj = __shfl(s_l, j);
            float xj = __shfl(ex_l, j);
            ushort4 hv = *(const ushort4*)(h + (long)sj * CH + lane * 4);
            acc.x += xj * bf16_to_f32(hv.x);
            acc.y += xj * bf16_to_f32(hv.y);
            acc.z += xj * bf16_to_f32(hv.z);
            acc.w += xj * bf16_to_f32(hv.w);
        }
    }
    float sum = sum_l;
#pragma unroll
    for (int off = 32; off > 0; off >>= 1) sum += __shfl_xor(sum, off);
    float inv = 1.f / fmaxf(sum, 1e-16f);

    float4 bv = *(const float4*)(bias + lane * 4);
    ushort4 ob;
    ob.x = f32_to_bf16_rne(selu_f(acc.x * inv + bv.x));
    ob.y = f32_to_bf16_rne(selu_f(acc.y * inv + bv.y));
    ob.z = f32_to_bf16_rne(selu_f(acc.z * inv + bv.z));
    ob.w = f32_to_bf16_rne(selu_f(acc.w * inv + bv.w));
    *(ushort4*)(out_bf + (long)node * CH + lane * 4) = ob;
}

// ---- fused pool + head: one block (1024 thr) per graph ---------------------
__global__ __launch_bounds__(1024) void pool_head_kernel(
        const ushort_t* __restrict__ h, const int* __restrict__ batch,
        const float* __restrict__ fc1W, const float* __restrict__ fc1b,
        const float* __restrict__ fc2W, const float* __restrict__ fc2b,
        float* __restrict__ out) {
    __shared__ float part[4][CH];
    __shared__ float row[CH];
    __shared__ float part2[8][HID];
    __shared__ float hrow[HID];
    __shared__ float logits[2];
    int g = blockIdx.x;
    int tid = threadIdx.x;
    int t = tid & 255;
    int quad = tid >> 8;              // 0..3
    int lo, hi;
    { int a = 0, b = N_NODES;
      while (a < b) { int mid = (a + b) >> 1; if (batch[mid] < g) a = mid + 1; else b = mid; }
      lo = a; }
    { int a = lo, b = N_NODES;
      while (a < b) { int mid = (a + b) >> 1; if (batch[mid] < g + 1) a = mid + 1; else b = mid; }
      hi = a; }
    float a0 = 0.f, a1 = 0.f;
    int i = lo + quad;
    for (; i + 4 < hi; i += 8) {
        a0 += bf16_to_f32(h[(long)i * CH + t]);
        a1 += bf16_to_f32(h[(long)(i + 4) * CH + t]);
    }
    for (; i < hi; i += 4) a0 += bf16_to_f32(h[(long)i * CH + t]);
    part[quad][t] = a0 + a1;
    __syncthreads();
    if (quad == 0) {
        float cnt = (float)(hi - lo);
        float acc = (part[0][t] + part[1][t]) + (part[2][t] + part[3][t]);
        row[t] = selu_f(acc / fmaxf(cnt, 1.f));
    }
    __syncthreads();
    {   // fc1: tid -> (seg = tid>>7 in 0..7, o = tid&127)
        int o = tid & 127;
        int seg = tid >> 7;
        float s = 0.f;
        int k0 = seg * 32;
        for (int k = k0; k < k0 + 32; ++k) s += row[k] * fc1W[k * HID + o];
        part2[seg][o] = s;
    }
    __syncthreads();
    if (tid < HID) {
        float s = fc1b[tid];
#pragma unroll
        for (int j = 0; j < 8; ++j) s += part2[j][tid];
        hrow[tid] = selu_f(s);
    }
    __syncthreads();
    if (tid < 2) {
        float a = fc2b[tid];
        for (int k = 0; k < HID; k++) a += hrow[k] * fc2W[k * 2 + tid];
        logits[tid] = a;
    }
    __syncthreads();
    if (tid < 2) {
        float m = fmaxf(logits[0], logits[1]);
        float lse = logf(expf(logits[0] - m) + expf(logits[1] - m)) + m;
        out[g * 2 + tid] = logits[tid] - lse;
    }
}

extern "C" void kernel_launch(void* const* d_in, const int* in_sizes, int n_in,
                              void* d_out, int out_size, void* d_ws, size_t ws_size,
                              hipStream_t stream) {
    const float* x      = (const float*)d_in[0];
    const int*   ei     = (const int*)d_in[1];
    const int*   batch  = (const int*)d_in[2];
    const float* W1     = (const float*)d_in[3];
    const float* att_l1 = (const float*)d_in[4];
    const float* att_r1 = (const float*)d_in[5];
    const float* b1     = (const float*)d_in[6];
    const float* W2     = (const float*)d_in[7];
    const float* att_l2 = (const float*)d_in[8];
    const float* att_r2 = (const float*)d_in[9];
    const float* b2     = (const float*)d_in[10];
    const float* fc1W   = (const float*)d_in[11];
    const float* fc1b   = (const float*)d_in[12];
    const float* fc2W   = (const float*)d_in[13];
    const float* fc2b   = (const float*)d_in[14];
    float* out = (float*)d_out;

    char* ws = (char*)d_ws;
    size_t off = 0;
    auto alloc = [&](size_t bytes) {
        void* p = ws + off;
        off += (bytes + 255) & ~(size_t)255;
        return p;
    };
    ushort_t* Hb1    = (ushort_t*)alloc((size_t)N_NODES * CH * 2);   // GEMM1 out; reused as agg2 out
    ushort_t* Zb2    = (ushort_t*)alloc((size_t)N_NODES * CH * 2);   // agg1 out = GEMM2 in
    ushort_t* Hb2    = (ushort_t*)alloc((size_t)N_NODES * CH * 2);   // GEMM2 out
    ushort_t* W1t    = (ushort_t*)alloc((size_t)CH * KP1 * 2);
    ushort_t* W2t    = (ushort_t*)alloc((size_t)CH * CH * 2);
    float*    a_src  = (float*)alloc((size_t)N_NODES * 4);
    float*    a_dst  = (float*)alloc((size_t)N_NODES * 4);
    int*      deg    = (int*)alloc((size_t)N_NODES * 4);   // cursor directly after
    int*      cursor = (int*)alloc(256);
    int*      basebuf= (int*)alloc((size_t)N_NODES * 4);
    int*      csrbuf = (int*)alloc((size_t)600000 * 4);    // counters + slots

    size_t deg_pad = ((size_t)N_NODES * 4 + 255) & ~(size_t)255;

    dim3 blk(256);
    int gemm_grid = (N_NODES + 63) / 64;        // 782 blocks, 256 thr each
    int edge_grid = (N_TOT + 255) / 256;        // 3321 fill blocks
    int node_grid = (N_NODES + 255) / 256;
    int agg_grid  = (N_NODES + 3) / 4;
    int wtdeg_grid = WT_BLKS + edge_grid;

    // ---------------- weight conversion + deg count ----------------
    hipMemsetAsync(deg, 0, deg_pad + 4, stream);          // deg + cursor
    convert_wt_deg<<<wtdeg_grid, blk, 0, stream>>>(W1, W1t, W2, W2t, ei, deg);
    reserve_k<<<node_grid, blk, 0, stream>>>(deg, basebuf, csrbuf, cursor, N_NODES);

    // ---------------- Layer 1 (x->bf16 fused; csr fill overlapped) ----------
    gemm_k<1, 1><<<gemm_grid + edge_grid, blk, 0, stream>>>(
        x, W1t, Hb1, att_l1, att_r1, a_src, a_dst, N_NODES, KP1,
        gemm_grid, ei, basebuf, csrbuf);
    gat_aggregate<<<agg_grid, blk, 0, stream>>>(basebuf, deg, csrbuf, a_src, a_dst,
                                                Hb1, b1, Zb2, N_NODES);

    // ---------------- Layer 2 (no fill code compiled in) ----------------
    gemm_k<0, 0><<<gemm_grid, blk, 0, stream>>>(
        Zb2, W2t, Hb2, att_l2, att_r2, a_src, a_dst, N_NODES, CH,
        gemm_grid, (const int*)nullptr, (const int*)nullptr, (int*)nullptr);
    gat_aggregate<<<agg_grid, blk, 0, stream>>>(basebuf, deg, csrbuf, a_src, a_dst,
                                                Hb2, b2, Hb1, N_NODES);

    // ---------------- Pool + head (fused, 1024 thr/graph) ----------------
    pool_head_kernel<<<N_GRAPHS, dim3(1024), 0, stream>>>(Hb1, batch, fc1W, fc1b,
                                                          fc2W, fc2b, out);
}

// Round 17
// 290.540 us; speedup vs baseline: 1.0443x; 1.0443x over previous
//
#include <hip/hip_runtime.h>
#include <hip/hip_bf16.h>

#define N_NODES 50000
#define N_EDGES 800000
#define N_TOT   (N_EDGES + N_NODES)
#define N_GRAPHS 256
#define F_IN 310
#define KP1 320          // F_IN padded to multiple of 32
#define CH 256
#define HID 128

typedef __attribute__((ext_vector_type(8))) short short8;
typedef __attribute__((ext_vector_type(4))) float f32x4;
typedef unsigned short ushort_t;

__device__ __forceinline__ float selu_f(float x) {
    const float scale = 1.0507009873554805f;
    const float alpha = 1.6732632423543772f;
    return x > 0.f ? scale * x : scale * alpha * (expm1f(x));
}

__device__ __forceinline__ ushort_t f32_to_bf16_rne(float f) {
    unsigned u = __float_as_uint(f);
    unsigned rounding = 0x7FFFu + ((u >> 16) & 1u);
    return (ushort_t)((u + rounding) >> 16);
}
__device__ __forceinline__ float bf16_to_f32(ushort_t v) {
    return __uint_as_float(((unsigned)v) << 16);
}

// ---- W conversions + deg_count fused into one launch -----------------------
#define WT_BLKS ((CH * KP1 + CH * CH + 255) / 256)
__global__ __launch_bounds__(256) void convert_wt_deg(
        const float* __restrict__ W1, ushort_t* __restrict__ W1t,
        const float* __restrict__ W2, ushort_t* __restrict__ W2t,
        const int* __restrict__ ei, int* __restrict__ deg) {
    int b = blockIdx.x;
    if (b < WT_BLKS) {
        int i = b * 256 + threadIdx.x;
        const int n1 = CH * KP1;
        if (i < n1) {
            int n = i / KP1, k = i % KP1;
            W1t[i] = (k < F_IN) ? f32_to_bf16_rne(W1[(long)k * CH + n]) : 0;
        } else {
            int j = i - n1;
            if (j >= CH * CH) return;
            int n = j / CH, k = j % CH;
            W2t[j] = f32_to_bf16_rne(W2[(long)k * CH + n]);
        }
    } else {
        int eid = (b - WT_BLKS) * 256 + threadIdx.x;
        if (eid >= N_TOT) return;
        int d = (eid < N_EDGES) ? ei[N_EDGES + eid] : eid - N_EDGES;
        atomicAdd(&deg[d], 1);
    }
}

// ------- MFMA GEMM 64x256 tile (4 waves of 64x64), 2-phase, 40KB LDS --------
// FILL=1 (layer 1 only): blocks >= gemmBlocks run csr_fill (latency-bound
// atomics overlapping the GEMM). FILL=0: fill code compiled OUT.
// LDS swizzle: chunk' = c ^ (r&3) ^ ((r>>2)&3); XOR involution applied on
// the GLOBAL source for glds (linear dest) and on the ds_write address for
// the f32-A path (rule #21).
template<int AF32, int FILL>
__global__ __launch_bounds__(256, 4) void gemm_k(
        const void* __restrict__ Asrc, const ushort_t* __restrict__ Bt,
        ushort_t* __restrict__ Cb, const float* __restrict__ att_l,
        const float* __restrict__ att_r, float* __restrict__ a_srcv,
        float* __restrict__ a_dstv, int M, int Kp, int gemmBlocks,
        const int* __restrict__ ei, int* __restrict__ fillpos,
        const int* __restrict__ startA, ushort_t* __restrict__ csr_src) {
    __shared__ __align__(16) ushort_t As[2][64 * 32];   //  8 KB
    __shared__ __align__(16) ushort_t Bs[2][256 * 32];  // 32 KB -> 40 KB total
    int tid = threadIdx.x;

    if constexpr (FILL) {
        if ((int)blockIdx.x >= gemmBlocks) {            // ---- csr_fill path
            int eid = ((int)blockIdx.x - gemmBlocks) * 256 + tid;
            if (eid < N_TOT) {
                if (eid < N_EDGES) {
                    int s = ei[eid], d = ei[N_EDGES + eid];
                    int p = atomicAdd(&fillpos[d], 1);
                    csr_src[p] = (ushort_t)s;
                } else {
                    int d = eid - N_EDGES;              // self-loop: fixed slot
                    csr_src[startA[d]] = (ushort_t)d;   // no atomic
                }
            }
            return;
        }
    }

    int row0 = blockIdx.x * 64;
    int w = tid >> 6, l = tid & 63;       // wave w = output col-block
    int lr = l & 15, lc = l >> 4;
    f32x4 acc[4][4] = {};

    int srow = l >> 2;                    // 0..15
    int sc = l & 3;
    int sx = sc ^ (srow & 3) ^ ((srow >> 2) & 3);       // pre-swizzled chunk
    int garow = row0 + w * 16 + srow; if (garow >= M) garow = M - 1;
    const ushort_t* gB[4];
#pragma unroll
    for (int g = 0; g < 4; ++g)
        gB[g] = Bt + (size_t)(w * 64 + g * 16 + srow) * Kp + sx * 8;
    int nt = Kp >> 5;

    const ushort_t* gA = nullptr;
    const float* xrow = nullptr;
    if (AF32) xrow = (const float*)Asrc + (size_t)garow * F_IN;
    else      gA = (const ushort_t*)Asrc + (size_t)garow * Kp + sx * 8;

    auto stageB = [&](int sel, int k0) {
#pragma unroll
        for (int g = 0; g < 4; ++g)
            __builtin_amdgcn_global_load_lds(
                (const __attribute__((address_space(1))) void*)(gB[g] + k0),
                (__attribute__((address_space(3))) void*)(&Bs[sel][(w * 64 + g * 16) * 32]), 16, 0, 0);
    };
    auto stageA_glds = [&](int sel, int k0) {
        __builtin_amdgcn_global_load_lds(
            (const __attribute__((address_space(1))) void*)(gA + k0),
            (__attribute__((address_space(3))) void*)(&As[sel][w * 16 * 32]), 16, 0, 0);
    };
    float va[8];
    auto loadA_f32 = [&](int k0) {
        int kc = k0 + sc * 8;             // natural chunk (write addr swizzled)
        if (kc + 8 <= F_IN) {             // x rows are 8B-aligned: float2 ok
#pragma unroll
            for (int j = 0; j < 4; ++j) {
                float2 p = *(const float2*)(xrow + kc + j * 2);
                va[j * 2] = p.x; va[j * 2 + 1] = p.y;
            }
        } else {                          // K tail (cols >= 310 -> 0)
#pragma unroll
            for (int j = 0; j < 8; ++j)
                va[j] = (kc + j < F_IN) ? xrow[kc + j] : 0.f;
        }
    };
    auto writeA = [&](int sel) {
        short8 s;
#pragma unroll
        for (int j = 0; j < 8; ++j) s[j] = (short)f32_to_bf16_rne(va[j]);
        *(short8*)(&As[sel][(w * 16 + srow) * 32 + sx * 8]) = s;
    };

    if (AF32) loadA_f32(0); else stageA_glds(0, 0);
    stageB(0, 0);
    if (AF32) writeA(0);
    __syncthreads();
    int cur = 0;
    for (int t = 0; t < nt; ++t) {
        int k1 = (t + 1) << 5;
        if (t + 1 < nt) {
            if (AF32) loadA_f32(k1); else stageA_glds(cur ^ 1, k1);
            stageB(cur ^ 1, k1);
        }
        short8 af[4], bfv[4];
#pragma unroll
        for (int mi = 0; mi < 4; ++mi) {
            int r = mi * 16 + lr;
            af[mi] = *(const short8*)(&As[cur][r * 32 + ((lc ^ (r & 3) ^ ((r >> 2) & 3)) * 8)]);
        }
#pragma unroll
        for (int ni = 0; ni < 4; ++ni) {
            int r = w * 64 + ni * 16 + lr;
            bfv[ni] = *(const short8*)(&Bs[cur][r * 32 + ((lc ^ (r & 3) ^ ((r >> 2) & 3)) * 8)]);
        }
#pragma unroll
        for (int mi = 0; mi < 4; ++mi)
#pragma unroll
            for (int ni = 0; ni < 4; ++ni)
                acc[mi][ni] = __builtin_amdgcn_mfma_f32_16x16x32_bf16(
                    af[mi], bfv[ni], acc[mi][ni], 0, 0, 0);
        if (AF32 && t + 1 < nt) writeA(cur ^ 1);
        __syncthreads();
        cur ^= 1;
    }

    // epilogue: reuse As (free after the loop's final barrier) as scratch
    float* s_pl = (float*)&As[0][0];
    float* s_pr = s_pl + 64;
    if (tid < 128) s_pl[tid] = 0.f;
    __syncthreads();
    float al[4], ar[4];
#pragma unroll
    for (int ni = 0; ni < 4; ++ni) {
        int col = w * 64 + ni * 16 + lr;
        al[ni] = att_l[col];
        ar[ni] = att_r[col];
    }
#pragma unroll
    for (int mi = 0; mi < 4; ++mi) {
        int lrow = mi * 16 + lc * 4;
#pragma unroll
        for (int q = 0; q < 4; ++q) {
            int grow = row0 + lrow + q;
            float pl = 0.f, pr = 0.f;
#pragma unroll
            for (int ni = 0; ni < 4; ++ni) {
                float v = acc[mi][ni][q];
                pl += v * al[ni];
                pr += v * ar[ni];
                if (grow < M)
                    Cb[(size_t)grow * CH + w * 64 + ni * 16 + lr] = f32_to_bf16_rne(v);
            }
#pragma unroll
            for (int off = 1; off < 16; off <<= 1) {
                pl += __shfl_xor(pl, off);
                pr += __shfl_xor(pr, off);
            }
            if (lr == 0) {
                atomicAdd(&s_pl[lrow + q], pl);
                atomicAdd(&s_pr[lrow + q], pr);
            }
        }
    }
    __syncthreads();
    if (tid < 64 && row0 + tid < M) {
        a_srcv[row0 + tid] = s_pl[tid];
        a_dstv[row0 + tid] = s_pr[tid];
    }
}

// ---------------- CSR build: range reserve (slot 0 = self-loop) -------------
__global__ __launch_bounds__(256) void reserve_k(
        const int* __restrict__ deg, int* __restrict__ start,
        int* __restrict__ fillpos, int* __restrict__ cursor, int n) {
    int i = blockIdx.x * blockDim.x + threadIdx.x;
    if (i >= n) return;
    int s = atomicAdd(cursor, deg[i]);
    start[i] = s;
    fillpos[i] = s + 1;          // slot s reserved for the self-loop
}

// ---- fused per-dst GAT aggregate: SINGLE edge pass (ushort csr) ------------
__global__ __launch_bounds__(256) void gat_aggregate(
        const int* __restrict__ start, const int* __restrict__ deg,
        const ushort_t* __restrict__ csr_src,
        const float* __restrict__ a_src, const float* __restrict__ a_dst,
        const ushort_t* __restrict__ h, const float* __restrict__ bias,
        ushort_t* __restrict__ out_bf, int n) {
    int wid = threadIdx.x >> 6;
    int lane = threadIdx.x & 63;
    int node = blockIdx.x * 4 + wid;
    if (node >= n) return;
    int s0 = start[node];
    int dg = deg[node];
    float ad = a_dst[node];

    float sum_l = 0.f;
    float4 acc = {0.f, 0.f, 0.f, 0.f};
    for (int c = 0; c < dg; c += 64) {
        int nc = min(64, dg - c);
        int s_l = 0; float ex_l = 0.f;
        if (lane < nc) {
            s_l = csr_src[s0 + c + lane];
            float e = a_src[s_l] + ad;
            e = fmaxf(e, 0.2f * e);
            ex_l = __expf(e);
            sum_l += ex_l;
        }
        int j = 0;
        for (; j + 8 <= nc; j += 8) {
            int si[8]; float xi[8]; ushort4 hv[8];
#pragma unroll
            for (int k = 0; k < 8; ++k) {
                si[k] = __shfl(s_l, j + k);
                xi[k] = __shfl(ex_l, j + k);
            }
#pragma unroll
            for (int k = 0; k < 8; ++k)
                hv[k] = *(const ushort4*)(h + (long)si[k] * CH + lane * 4);
#pragma unroll
            for (int k = 0; k < 8; ++k) {
                acc.x += xi[k] * bf16_to_f32(hv[k].x);
                acc.y += xi[k] * bf16_to_f32(hv[k].y);
                acc.z += xi[k] * bf16_to_f32(hv[k].z);
                acc.w += xi[k] * bf16_to_f32(hv[k].w);
            }
        }
        for (; j < nc; ++j) {
            int sj = __shfl(s_l, j);
            float xj = __shfl(ex_l, j);
            ushort4 hv = *(const ushort4*)(h + (long)sj * CH + lane * 4);
            acc.x += xj * bf16_to_f32(hv.x);
            acc.y += xj * bf16_to_f32(hv.y);
            acc.z += xj * bf16_to_f32(hv.z);
            acc.w += xj * bf16_to_f32(hv.w);
        }
    }
    float sum = sum_l;
#pragma unroll
    for (int off = 32; off > 0; off >>= 1) sum += __shfl_xor(sum, off);
    float inv = 1.f / fmaxf(sum, 1e-16f);

    float4 bv = *(const float4*)(bias + lane * 4);
    ushort4 ob;
    ob.x = f32_to_bf16_rne(selu_f(acc.x * inv + bv.x));
    ob.y = f32_to_bf16_rne(selu_f(acc.y * inv + bv.y));
    ob.z = f32_to_bf16_rne(selu_f(acc.z * inv + bv.z));
    ob.w = f32_to_bf16_rne(selu_f(acc.w * inv + bv.w));
    *(ushort4*)(out_bf + (long)node * CH + lane * 4) = ob;
}

// ---- fused pool + head: one block (1024 thr) per graph ---------------------
__global__ __launch_bounds__(1024) void pool_head_kernel(
        const ushort_t* __restrict__ h, const int* __restrict__ batch,
        const float* __restrict__ fc1W, const float* __restrict__ fc1b,
        const float* __restrict__ fc2W, const float* __restrict__ fc2b,
        float* __restrict__ out) {
    __shared__ float part[4][CH];
    __shared__ float row[CH];
    __shared__ float part2[8][HID];
    __shared__ float hrow[HID];
    __shared__ float logits[2];
    int g = blockIdx.x;
    int tid = threadIdx.x;
    int t = tid & 255;
    int quad = tid >> 8;              // 0..3
    int lo, hi;
    { int a = 0, b = N_NODES;
      while (a < b) { int mid = (a + b) >> 1; if (batch[mid] < g) a = mid + 1; else b = mid; }
      lo = a; }
    { int a = lo, b = N_NODES;
      while (a < b) { int mid = (a + b) >> 1; if (batch[mid] < g + 1) a = mid + 1; else b = mid; }
      hi = a; }
    float a0 = 0.f, a1 = 0.f;
    int i = lo + quad;
    for (; i + 4 < hi; i += 8) {
        a0 += bf16_to_f32(h[(long)i * CH + t]);
        a1 += bf16_to_f32(h[(long)(i + 4) * CH + t]);
    }
    for (; i < hi; i += 4) a0 += bf16_to_f32(h[(long)i * CH + t]);
    part[quad][t] = a0 + a1;
    __syncthreads();
    if (quad == 0) {
        float cnt = (float)(hi - lo);
        float acc = (part[0][t] + part[1][t]) + (part[2][t] + part[3][t]);
        row[t] = selu_f(acc / fmaxf(cnt, 1.f));
    }
    __syncthreads();
    {   // fc1: tid -> (seg = tid>>7 in 0..7, o = tid&127)
        int o = tid & 127;
        int seg = tid >> 7;
        float s = 0.f;
        int k0 = seg * 32;
        for (int k = k0; k < k0 + 32; ++k) s += row[k] * fc1W[k * HID + o];
        part2[seg][o] = s;
    }
    __syncthreads();
    if (tid < HID) {
        float s = fc1b[tid];
#pragma unroll
        for (int j = 0; j < 8; ++j) s += part2[j][tid];
        hrow[tid] = selu_f(s);
    }
    __syncthreads();
    if (tid < 2) {
        float a = fc2b[tid];
        for (int k = 0; k < HID; k++) a += hrow[k] * fc2W[k * 2 + tid];
        logits[tid] = a;
    }
    __syncthreads();
    if (tid < 2) {
        float m = fmaxf(logits[0], logits[1]);
        float lse = logf(expf(logits[0] - m) + expf(logits[1] - m)) + m;
        out[g * 2 + tid] = logits[tid] - lse;
    }
}

extern "C" void kernel_launch(void* const* d_in, const int* in_sizes, int n_in,
                              void* d_out, int out_size, void* d_ws, size_t ws_size,
                              hipStream_t stream) {
    const float* x      = (const float*)d_in[0];
    const int*   ei     = (const int*)d_in[1];
    const int*   batch  = (const int*)d_in[2];
    const float* W1     = (const float*)d_in[3];
    const float* att_l1 = (const float*)d_in[4];
    const float* att_r1 = (const float*)d_in[5];
    const float* b1     = (const float*)d_in[6];
    const float* W2     = (const float*)d_in[7];
    const float* att_l2 = (const float*)d_in[8];
    const float* att_r2 = (const float*)d_in[9];
    const float* b2     = (const float*)d_in[10];
    const float* fc1W   = (const float*)d_in[11];
    const float* fc1b   = (const float*)d_in[12];
    const float* fc2W   = (const float*)d_in[13];
    const float* fc2b   = (const float*)d_in[14];
    float* out = (float*)d_out;

    char* ws = (char*)d_ws;
    size_t off = 0;
    auto alloc = [&](size_t bytes) {
        void* p = ws + off;
        off += (bytes + 255) & ~(size_t)255;
        return p;
    };
    ushort_t* Hb1    = (ushort_t*)alloc((size_t)N_NODES * CH * 2);   // GEMM1 out; reused as agg2 out
    ushort_t* Zb2    = (ushort_t*)alloc((size_t)N_NODES * CH * 2);   // agg1 out = GEMM2 in
    ushort_t* Hb2    = (ushort_t*)alloc((size_t)N_NODES * CH * 2);   // GEMM2 out
    ushort_t* W1t    = (ushort_t*)alloc((size_t)CH * KP1 * 2);
    ushort_t* W2t    = (ushort_t*)alloc((size_t)CH * CH * 2);
    float*    a_src  = (float*)alloc((size_t)N_NODES * 4);
    float*    a_dst  = (float*)alloc((size_t)N_NODES * 4);
    int*      deg    = (int*)alloc((size_t)N_NODES * 4);   // cursor directly after
    int*      cursor = (int*)alloc(256);
    int*      startA = (int*)alloc((size_t)N_NODES * 4);
    int*      fillpos= (int*)alloc((size_t)N_NODES * 4);
    ushort_t* csr_src= (ushort_t*)alloc((size_t)N_TOT * 2);

    size_t deg_pad = ((size_t)N_NODES * 4 + 255) & ~(size_t)255;

    dim3 blk(256);
    int gemm_grid = (N_NODES + 63) / 64;        // 782 blocks, 256 thr each
    int edge_grid = (N_TOT + 255) / 256;        // 3321 fill blocks
    int node_grid = (N_NODES + 255) / 256;
    int agg_grid  = (N_NODES + 3) / 4;
    int wtdeg_grid = WT_BLKS + edge_grid;

    // ---------------- weight conversion + deg count ----------------
    hipMemsetAsync(deg, 0, deg_pad + 4, stream);          // deg + cursor
    convert_wt_deg<<<wtdeg_grid, blk, 0, stream>>>(W1, W1t, W2, W2t, ei, deg);
    reserve_k<<<node_grid, blk, 0, stream>>>(deg, startA, fillpos, cursor, N_NODES);

    // ---------------- Layer 1 (x->bf16 fused; csr_fill overlapped) ----------
    gemm_k<1, 1><<<gemm_grid + edge_grid, blk, 0, stream>>>(
        x, W1t, Hb1, att_l1, att_r1, a_src, a_dst, N_NODES, KP1,
        gemm_grid, ei, fillpos, startA, csr_src);
    gat_aggregate<<<agg_grid, blk, 0, stream>>>(startA, deg, csr_src, a_src, a_dst,
                                                Hb1, b1, Zb2, N_NODES);

    // ---------------- Layer 2 (no fill code compiled in) ----------------
    gemm_k<0, 0><<<gemm_grid, blk, 0, stream>>>(
        Zb2, W2t, Hb2, att_l2, att_r2, a_src, a_dst, N_NODES, CH,
        gemm_grid, (const int*)nullptr, (int*)nullptr,
        (const int*)nullptr, (ushort_t*)nullptr);
    gat_aggregate<<<agg_grid, blk, 0, stream>>>(startA, deg, csr_src, a_src, a_dst,
                                                Hb2, b2, Hb1, N_NODES);

    // ---------------- Pool + head (fused, 1024 thr/graph) ----------------
    pool_head_kernel<<<N_GRAPHS, dim3(1024), 0, stream>>>(Hb1, batch, fc1W, fc1b,
                                                          fc2W, fc2b, out);
}